// Round 10
// baseline (226.556 us; speedup 1.0000x reference)
//
#include <hip/hip_runtime.h>

#define B_ 4
#define S_ 2048
#define D_ 1024
#define H_ 16
#define E_ 64
#define M_ (B_*S_)   // 8192

typedef __attribute__((ext_vector_type(8))) short short8;   // 8 bf16 = 4 VGPRs (MFMA A/B frag)
typedef __attribute__((ext_vector_type(4))) float floatx4;  // MFMA C/D frag

// async global->LDS, 16B per lane; dest must be linear (wave base + lane*16)
#define GLD16(g, l) __builtin_amdgcn_global_load_lds( \
    (const __attribute__((address_space(1))) unsigned*)(g), \
    (__attribute__((address_space(3))) unsigned*)(l), 16, 0, 0)

__device__ __forceinline__ ushort f2b(float f) {   // fp32 -> bf16 RNE
    union { float f; unsigned u; } v; v.f = f;
    unsigned r = v.u + 0x7fffu + ((v.u >> 16) & 1u);
    return (ushort)(r >> 16);
}
__device__ __forceinline__ unsigned cvt_pk_bf16(float lo, float hi) {  // 2xf32 -> packed bf16x2
    unsigned r;
    asm("v_cvt_pk_bf16_f32 %0, %1, %2" : "=v"(r) : "v"(lo), "v"(hi));
    return r;
}
__device__ __forceinline__ float fast_exp2(float x) {
#if __has_builtin(__builtin_amdgcn_exp2f)
    return __builtin_amdgcn_exp2f(x);
#else
    float r; asm("v_exp_f32 %0, %1" : "=v"(r) : "v"(x)); return r;
#endif
}

// ---------------- plain cast fp32 -> bf16 (vector8) ----------------
__global__ __launch_bounds__(256) void cast_bf16(const float* __restrict__ in,
                                                 ushort* __restrict__ out, int n8) {
    int i = blockIdx.x * 256 + threadIdx.x;
    int stride = gridDim.x * 256;
    for (; i < n8; i += stride) {
        float4 a = ((const float4*)in)[2 * i];
        float4 b = ((const float4*)in)[2 * i + 1];
        short8 o;
        o[0] = (short)f2b(a.x); o[1] = (short)f2b(a.y);
        o[2] = (short)f2b(a.z); o[3] = (short)f2b(a.w);
        o[4] = (short)f2b(b.x); o[5] = (short)f2b(b.y);
        o[6] = (short)f2b(b.z); o[7] = (short)f2b(b.w);
        ((short8*)out)[i] = o;
    }
}

// ---------------- W cast+transpose: [48][D][E] fp32 -> [48][E][D] bf16 ----------------
__global__ __launch_bounds__(256) void transpose_w(const float* __restrict__ Wq,
                                                   const float* __restrict__ Wk,
                                                   const float* __restrict__ Wv,
                                                   ushort* __restrict__ wt) {
    int g = blockIdx.y;                 // 0..47 (w*16+h)
    int d0 = blockIdx.x * 64;
    const float* W = (g < 16 ? Wq : (g < 32 ? Wk : Wv)) + (size_t)(g & 15) * (D_ * E_);
    __shared__ __align__(16) ushort T[64 * 80];   // T[e][d-col], pitch 80
    int t = threadIdx.x;
    #pragma unroll
    for (int it = 0; it < 4; ++it) {               // 64 d-rows x 16 float4 cols
        int i = it * 256 + t;
        int r = i >> 4, c = i & 15;
        float4 x = *(const float4*)(W + (size_t)(d0 + r) * E_ + c * 4);
        T[(c * 4 + 0) * 80 + r] = f2b(x.x);
        T[(c * 4 + 1) * 80 + r] = f2b(x.y);
        T[(c * 4 + 2) * 80 + r] = f2b(x.z);
        T[(c * 4 + 3) * 80 + r] = f2b(x.w);
    }
    __syncthreads();
    #pragma unroll
    for (int it = 0; it < 2; ++it) {               // 64 e-rows x 8 chunks of 8
        int i = it * 256 + t;
        int e = i >> 3, c = i & 7;
        short8 x = *(const short8*)&T[e * 80 + c * 8];
        *(short8*)&wt[((size_t)g * E_ + e) * D_ + d0 + c * 8] = x;
    }
}

// ---------------- V transpose: [bh][S][E] -> [bh][E][S] (bf16) ----------------
__global__ __launch_bounds__(256) void transpose_v(const ushort* __restrict__ v,
                                                   ushort* __restrict__ vt) {
    int s0 = blockIdx.x * 64;
    int bh = blockIdx.y;
    __shared__ __align__(16) ushort T[64 * 80];   // T[e][s-col]
    int t = threadIdx.x;
    #pragma unroll
    for (int it = 0; it < 2; ++it) {
        int i = it * 256 + t;
        int r = i >> 3, c = i & 7;                 // s-row r, e-chunk c
        short8 x = *(const short8*)&v[((size_t)bh * S_ + s0 + r) * E_ + c * 8];
        #pragma unroll
        for (int j = 0; j < 8; ++j) T[(c * 8 + j) * 80 + r] = (ushort)x[j];
    }
    __syncthreads();
    #pragma unroll
    for (int it = 0; it < 2; ++it) {
        int i = it * 256 + t;
        int e = i >> 3, c = i & 7;
        short8 x = *(const short8*)&T[e * 80 + c * 8];
        *(short8*)&vt[((size_t)bh * E_ + e) * S_ + s0 + c * 8] = x;
    }
}

// ---------------- QKV GEMM: [8192 x 1024] x [1024 x 64] per (w,h), bf16 MFMA ----------------
__global__ __launch_bounds__(256) void gemm_qkv(const ushort* __restrict__ xb,
                                                const ushort* __restrict__ wt,
                                                ushort* __restrict__ qkv) {
    const int m0 = blockIdx.x * 256;
    const int wh = blockIdx.y;           // 0..47
    const ushort* Wg = wt + (size_t)wh * (E_ * D_);
    ushort* outw = qkv + (size_t)(wh >> 4) * ((size_t)B_ * H_ * S_ * E_);
    const int h = wh & 15;

    __shared__ __align__(16) ushort As[256 * 32];   // [256][32] swizzled
    __shared__ __align__(16) ushort Bs[64 * 32];    // [64][32]  swizzled

    const int t = threadIdx.x, l = t & 63, wid = t >> 6;
    floatx4 acc[4][4] = {};

    for (int k0 = 0; k0 < D_; k0 += 32) {
        __syncthreads();
        #pragma unroll
        for (int it = 0; it < 4; ++it) {            // A: 1024 chunks
            int i = it * 256 + t;
            int r = i >> 2, cs = i & 3;
            int c = cs ^ ((r >> 1) & 3);
            GLD16(xb + (size_t)(m0 + r) * D_ + k0 + c * 8, &As[i * 8]);
        }
        {                                            // B: 256 chunks
            int r = t >> 2, cs = t & 3;
            int c = cs ^ ((r >> 1) & 3);
            GLD16(Wg + (size_t)r * D_ + k0 + c * 8, &Bs[t * 8]);
        }
        __syncthreads();

        short8 af[4], bf[4];
        #pragma unroll
        for (int mf = 0; mf < 4; ++mf) {
            int row = wid * 64 + 16 * mf + (l & 15);
            int c = (l >> 4) ^ ((row >> 1) & 3);
            af[mf] = *(const short8*)&As[row * 32 + c * 8];
        }
        #pragma unroll
        for (int nf = 0; nf < 4; ++nf) {
            int row = 16 * nf + (l & 15);
            int c = (l >> 4) ^ ((row >> 1) & 3);
            bf[nf] = *(const short8*)&Bs[row * 32 + c * 8];
        }
        #pragma unroll
        for (int mf = 0; mf < 4; ++mf)
            #pragma unroll
            for (int nf = 0; nf < 4; ++nf)
                acc[mf][nf] = __builtin_amdgcn_mfma_f32_16x16x32_bf16(af[mf], bf[nf], acc[mf][nf], 0, 0, 0);
    }

    #pragma unroll
    for (int mf = 0; mf < 4; ++mf)
        #pragma unroll
        for (int nf = 0; nf < 4; ++nf)
            #pragma unroll
            for (int r = 0; r < 4; ++r) {
                int m = m0 + wid * 64 + 16 * mf + (l >> 4) * 4 + r;
                int b = m >> 11, s = m & (S_ - 1);
                int e = 16 * nf + (l & 15);
                outw[((size_t)((b << 4) + h) * S_ + s) * E_ + e] = f2b(acc[mf][nf][r]);
            }
}

// ---------------- Flash attention (causal), bf16 MFMA, 2-phase pipelined ----------------
// grid: 1024 1-D blocks. Block n: x = n>>6 (0..15), bh = n&63 (XCD = n%8 = bh%8).
// Balanced pairs {x, 31-x} = 33 KV-tile-units per block; 1024/256 = 4 blocks/CU.
// LDS = 40 KB (Q-staging buffer REUSED as the per-wave P buffer: Q fragments live in
// registers after the prologue, so Qs is dead during the jt loop; each wave touches
// only its own 16x64 quarter of QP for P, and barriers separate staging from use)
// -> 4 blocks/CU resident (vs 2-3 at 48 KB). Tests the LDS-residency-cap hypothesis.
__global__ __launch_bounds__(256) void flash(const ushort* __restrict__ qg,
                                             const ushort* __restrict__ kg,
                                             const ushort* __restrict__ vtg,
                                             ushort* __restrict__ attn) {
    const int n = blockIdx.x;
    const int x = n >> 6;          // 0..15
    const int bh = n & 63;
    const int b = bh >> 4, h = bh & 15;
    const ushort* qb = qg + (size_t)bh * (S_ * E_);
    const ushort* kb = kg + (size_t)bh * (S_ * E_);
    const ushort* vb = vtg + (size_t)bh * (E_ * S_);

    __shared__ __align__(16) ushort QP[64 * 64];      // Q staging [q][e] swizzled, THEN per-wave P [wid][16][64]
    __shared__ __align__(16) ushort Ks[2][64 * 64];   // [t][e]   swizzled, double-buffered
    __shared__ __align__(16) ushort Vs[2][64 * 64];   // [e][j]   swizzled, double-buffered

    const int t = threadIdx.x, l = t & 63, wid = t >> 6;
    const float SC = 0.18033688f;                  // (1/sqrt(E)) * log2(e)
    const float NEG_INF = -__builtin_inff();
    const int ri_base = wid * 16 + ((l >> 4) << 2);
    const int qts[2] = {x, 31 - x};
    ushort* Pw = &QP[wid * 1024];                  // this wave's 16x64 P quarter

    #pragma unroll 1
    for (int qi = 0; qi < 2; ++qi) {
        const int qt = qts[qi];

        // prologue: stage Q + first K/V tile
        #pragma unroll
        for (int it = 0; it < 2; ++it) {
            int i = it * 256 + t;
            int r = i >> 3, cs = i & 7, c = cs ^ (r & 7);
            GLD16(qb + (size_t)(qt * 64 + r) * E_ + c * 8, &QP[i * 8]);
            GLD16(kb + (size_t)r * E_ + c * 8, &Ks[0][i * 8]);
            GLD16(vb + (size_t)r * S_ + c * 8, &Vs[0][i * 8]);
        }
        __syncthreads();

        short8 qf[2];   // Q fragment lives in registers; QP is dead for Q after this
        #pragma unroll
        for (int ks = 0; ks < 2; ++ks) {
            int row = wid * 16 + (l & 15);
            int c = ((l >> 4) + 4 * ks) ^ (row & 7);
            qf[ks] = *(const short8*)&QP[row * 64 + c * 8];
        }

        floatx4 o[4] = {};
        float mr[4], lr[4];
        #pragma unroll
        for (int r = 0; r < 4; ++r) { mr[r] = NEG_INF; lr[r] = 0.f; }

        int buf = 0;
        for (int jt = 0; jt <= qt; ++jt) {
            // issue next tile's staging BEFORE compute (latency hides under compute)
            if (jt < qt) {
                #pragma unroll
                for (int it = 0; it < 2; ++it) {
                    int i = it * 256 + t;
                    int r = i >> 3, cs = i & 7, c = cs ^ (r & 7);
                    GLD16(kb + (size_t)((jt + 1) * 64 + r) * E_ + c * 8, &Ks[buf ^ 1][i * 8]);
                    GLD16(vb + (size_t)r * S_ + (jt + 1) * 64 + c * 8, &Vs[buf ^ 1][i * 8]);
                }
            }

            // S = Q K^T on current buffer (raw scores)
            floatx4 s[4] = {};
            #pragma unroll
            for (int nf = 0; nf < 4; ++nf) {
                #pragma unroll
                for (int ks = 0; ks < 2; ++ks) {
                    int row = 16 * nf + (l & 15);
                    int c = ((l >> 4) + 4 * ks) ^ (row & 7);
                    short8 kf = *(const short8*)&Ks[buf][row * 64 + c * 8];
                    s[nf] = __builtin_amdgcn_mfma_f32_16x16x32_bf16(qf[ks], kf, s[nf], 0, 0, 0);
                }
            }

            // causal mask on diagonal tile only (raw scores, -inf)
            if (jt == qt) {
                #pragma unroll
                for (int nf = 0; nf < 4; ++nf) {
                    int cj = 16 * nf + (l & 15);
                    #pragma unroll
                    for (int r = 0; r < 4; ++r)
                        if (cj > ri_base + r) s[nf][r] = NEG_INF;
                }
            }

            // row max on raw scores + defer-max check
            float mxr[4]; bool ok = true;
            #pragma unroll
            for (int r = 0; r < 4; ++r) {
                float mx = fmaxf(fmaxf(s[0][r], s[1][r]), fmaxf(s[2][r], s[3][r]));
                mx = fmaxf(mx, __shfl_xor(mx, 1));
                mx = fmaxf(mx, __shfl_xor(mx, 2));
                mx = fmaxf(mx, __shfl_xor(mx, 4));
                mx = fmaxf(mx, __shfl_xor(mx, 8));
                mxr[r] = mx;
                ok = ok && ((mx - mr[r]) * SC <= 8.0f);
            }

            if (!__all(ok)) {   // rescale path (rare after warm-up)
                #pragma unroll
                for (int r = 0; r < 4; ++r) {
                    float mn = fmaxf(mr[r], mxr[r]);
                    float al = fast_exp2((mr[r] - mn) * SC);
                    mr[r] = mn;
                    lr[r] *= al;
                    #pragma unroll
                    for (int nf = 0; nf < 4; ++nf) o[nf][r] *= al;
                }
            }

            // exp2(fma) + lane-partial row sums (no shfl here)
            #pragma unroll
            for (int r = 0; r < 4; ++r) {
                float nm = -mr[r] * SC;
                float rs = 0.f;
                #pragma unroll
                for (int nf = 0; nf < 4; ++nf) {
                    float p = fast_exp2(fmaf(s[nf][r], SC, nm));
                    s[nf][r] = p;
                    rs += p;
                }
                lr[r] += rs;
            }

            // P -> wave-private quarter of QP (packed bf16 cvt, swizzled u16 writes)
            #pragma unroll
            for (int nf = 0; nf < 4; ++nf) {
                int col = 16 * nf + (l & 15);
                int sw_hi = (col >> 3) << 3;   // swizzle chunk base, col&7 fixed
                #pragma unroll
                for (int rp = 0; rp < 2; ++rp) {
                    unsigned pk = cvt_pk_bf16(s[nf][2 * rp], s[nf][2 * rp + 1]);
                    int row0 = (l >> 4) * 4 + 2 * rp;
                    int a0 = row0 * 64 + ((sw_hi >> 3) ^ (row0 & 7)) * 8 + (col & 7);
                    int a1 = (row0 + 1) * 64 + ((sw_hi >> 3) ^ ((row0 + 1) & 7)) * 8 + (col & 7);
                    Pw[a0] = (ushort)pk;
                    Pw[a1] = (ushort)(pk >> 16);
                }
            }

            // O += P V
            short8 pf[2];
            #pragma unroll
            for (int ks = 0; ks < 2; ++ks) {
                int row = l & 15;
                int c = ((l >> 4) + 4 * ks) ^ (row & 7);
                pf[ks] = *(const short8*)&Pw[row * 64 + c * 8];
            }
            #pragma unroll
            for (int nf = 0; nf < 4; ++nf) {
                #pragma unroll
                for (int ks = 0; ks < 2; ++ks) {
                    int row = 16 * nf + (l & 15);
                    int c = ((l >> 4) + 4 * ks) ^ (row & 7);
                    short8 vf = *(const short8*)&Vs[buf][row * 64 + c * 8];
                    o[nf] = __builtin_amdgcn_mfma_f32_16x16x32_bf16(pf[ks], vf, o[nf], 0, 0, 0);
                }
            }

            __syncthreads();   // drains this iteration's prefetch (vmcnt) + protects buf^1
            buf ^= 1;
        }

        // epilogue: reduce lane-partial sums, normalize, bounce via Pw for coalesced writes
        #pragma unroll
        for (int r = 0; r < 4; ++r) {
            float rs = lr[r];
            rs += __shfl_xor(rs, 1);
            rs += __shfl_xor(rs, 2);
            rs += __shfl_xor(rs, 4);
            rs += __shfl_xor(rs, 8);
            lr[r] = 1.0f / rs;
        }
        #pragma unroll
        for (int nf = 0; nf < 4; ++nf) {
            int col = 16 * nf + (l & 15);
            #pragma unroll
            for (int rp = 0; rp < 2; ++rp) {
                unsigned pk = cvt_pk_bf16(o[nf][2 * rp] * lr[2 * rp],
                                          o[nf][2 * rp + 1] * lr[2 * rp + 1]);
                int row0 = (l >> 4) * 4 + 2 * rp;
                int a0 = row0 * 64 + (((col >> 3)) ^ (row0 & 7)) * 8 + (col & 7);
                int a1 = (row0 + 1) * 64 + (((col >> 3)) ^ ((row0 + 1) & 7)) * 8 + (col & 7);
                Pw[a0] = (ushort)pk;
                Pw[a1] = (ushort)(pk >> 16);
            }
        }
        #pragma unroll
        for (int it = 0; it < 2; ++it) {               // 16 rows x 8 chunks per wave
            int i = it * 64 + l;
            int row = i >> 3, cc = i & 7;
            int c = cc ^ (row & 7);
            short8 vv = *(const short8*)&Pw[row * 64 + c * 8];
            int s_abs = qt * 64 + wid * 16 + row;
            *(short8*)&attn[((size_t)(b * S_ + s_abs)) * D_ + h * E_ + cc * 8] = vv;
        }
        __syncthreads();   // all waves done with QP before next q-tile's Q staging
    }
}

// ---------------- output projection: [8192x1024] x Wp^T + bp, bf16 MFMA, fp32 out ----------------
__global__ __launch_bounds__(256) void out_proj(const ushort* __restrict__ a,
                                                const ushort* __restrict__ wpb,
                                                const float* __restrict__ bp,
                                                float* __restrict__ out) {
    const int m0 = blockIdx.x * 128;
    const int n0 = blockIdx.y * 128;

    __shared__ __align__(16) ushort As[128 * 32];
    __shared__ __align__(16) ushort Bs[128 * 32];

    const int t = threadIdx.x, l = t & 63, wid = t >> 6;
    const int wm = (wid & 1) * 64, wn = (wid >> 1) * 64;
    floatx4 acc[4][4] = {};

    for (int k0 = 0; k0 < D_; k0 += 32) {
        __syncthreads();
        #pragma unroll
        for (int it = 0; it < 2; ++it) {
            int i = it * 256 + t;
            int r = i >> 2, cs = i & 3;
            int c = cs ^ ((r >> 1) & 3);
            GLD16(a + (size_t)(m0 + r) * D_ + k0 + c * 8, &As[i * 8]);
            GLD16(wpb + (size_t)(n0 + r) * D_ + k0 + c * 8, &Bs[i * 8]);
        }
        __syncthreads();

        short8 af[4], bf[4];
        #pragma unroll
        for (int mf = 0; mf < 4; ++mf) {
            int row = wm + 16 * mf + (l & 15);
            int c = (l >> 4) ^ ((row >> 1) & 3);
            af[mf] = *(const short8*)&As[row * 32 + c * 8];
        }
        #pragma unroll
        for (int nf = 0; nf < 4; ++nf) {
            int row = wn + 16 * nf + (l & 15);
            int c = (l >> 4) ^ ((row >> 1) & 3);
            bf[nf] = *(const short8*)&Bs[row * 32 + c * 8];
        }
        #pragma unroll
        for (int mf = 0; mf < 4; ++mf)
            #pragma unroll
            for (int nf = 0; nf < 4; ++nf)
                acc[mf][nf] = __builtin_amdgcn_mfma_f32_16x16x32_bf16(af[mf], bf[nf], acc[mf][nf], 0, 0, 0);
    }

    #pragma unroll
    for (int nf = 0; nf < 4; ++nf) {
        int col = n0 + wn + 16 * nf + (l & 15);
        float bias = bp[col];
        #pragma unroll
        for (int mf = 0; mf < 4; ++mf)
            #pragma unroll
            for (int r = 0; r < 4; ++r) {
                int m = m0 + wm + 16 * mf + (l >> 4) * 4 + r;
                out[(size_t)m * D_ + col] = acc[mf][nf][r] + bias;
            }
    }
}

extern "C" void kernel_launch(void* const* d_in, const int* in_sizes, int n_in,
                              void* d_out, int out_size, void* d_ws, size_t ws_size,
                              hipStream_t stream) {
    const float* x  = (const float*)d_in[0];
    const float* Wq = (const float*)d_in[1];
    const float* Wk = (const float*)d_in[2];
    const float* Wv = (const float*)d_in[3];
    const float* Wp = (const float*)d_in[4];
    const float* bp = (const float*)d_in[5];

    ushort* ws = (ushort*)d_ws;
    const size_t NX  = (size_t)M_ * D_;          // 8M
    const size_t NW  = (size_t)48 * E_ * D_;     // 3.15M
    const size_t NP  = (size_t)D_ * D_;          // 1M
    const size_t QSZ = (size_t)B_ * H_ * S_ * E_;// 8M
    ushort* xb    = ws;
    ushort* wt    = xb + NX;
    ushort* wpb   = wt + NW;
    ushort* qkvb  = wpb + NP;        // q | k | v
    ushort* vt    = qkvb + 3 * QSZ;
    ushort* attnb = vt + QSZ;        // total ~104 MB

    cast_bf16  <<<2048, 256, 0, stream>>>(x, xb, (int)(NX / 8));
    cast_bf16  <<<512, 256, 0, stream>>>(Wp, wpb, (int)(NP / 8));
    transpose_w<<<dim3(16, 48), 256, 0, stream>>>(Wq, Wk, Wv, wt);
    gemm_qkv   <<<dim3(M_ / 256, 48), 256, 0, stream>>>(xb, wt, qkvb);
    transpose_v<<<dim3(S_ / 64, B_ * H_), 256, 0, stream>>>(qkvb + 2 * QSZ, vt);
    flash      <<<1024, 256, 0, stream>>>(qkvb, qkvb + QSZ, vt, attnb);
    out_proj   <<<dim3(M_ / 128, D_ / 128), 256, 0, stream>>>(attnb, wpb, bp, (float*)d_out);
}

// Round 11
// 209.931 us; speedup vs baseline: 1.0792x; 1.0792x over previous
//
#include <hip/hip_runtime.h>

#define B_ 4
#define S_ 2048
#define D_ 1024
#define H_ 16
#define E_ 64
#define M_ (B_*S_)   // 8192

typedef __attribute__((ext_vector_type(8))) short short8;   // 8 bf16 = 4 VGPRs (MFMA A/B frag)
typedef __attribute__((ext_vector_type(4))) float floatx4;  // MFMA C/D frag

// async global->LDS, 16B per lane; dest must be linear (wave base + lane*16)
#define GLD16(g, l) __builtin_amdgcn_global_load_lds( \
    (const __attribute__((address_space(1))) unsigned*)(g), \
    (__attribute__((address_space(3))) unsigned*)(l), 16, 0, 0)

__device__ __forceinline__ ushort f2b(float f) {   // fp32 -> bf16 RNE
    union { float f; unsigned u; } v; v.f = f;
    unsigned r = v.u + 0x7fffu + ((v.u >> 16) & 1u);
    return (ushort)(r >> 16);
}
__device__ __forceinline__ unsigned cvt_pk_bf16(float lo, float hi) {  // 2xf32 -> packed bf16x2
    unsigned r;
    asm("v_cvt_pk_bf16_f32 %0, %1, %2" : "=v"(r) : "v"(lo), "v"(hi));
    return r;
}
__device__ __forceinline__ float fast_exp2(float x) {
#if __has_builtin(__builtin_amdgcn_exp2f)
    return __builtin_amdgcn_exp2f(x);
#else
    float r; asm("v_exp_f32 %0, %1" : "=v"(r) : "v"(x)); return r;
#endif
}

// 16-lane-row reductions on the VALU pipe via DPP (no ds_swizzle/bpermute -> keeps LDS pipe free).
// steps: quad_perm xor1 (0xB1), quad_perm xor2 (0x4E), row_ror:4 (0x124), row_ror:8 (0x128).
__device__ __forceinline__ float dpp_max16(float x) {
    int v;
    v = __builtin_amdgcn_update_dpp(0, __float_as_int(x), 0xB1, 0xF, 0xF, true);
    x = fmaxf(x, __int_as_float(v));
    v = __builtin_amdgcn_update_dpp(0, __float_as_int(x), 0x4E, 0xF, 0xF, true);
    x = fmaxf(x, __int_as_float(v));
    v = __builtin_amdgcn_update_dpp(0, __float_as_int(x), 0x124, 0xF, 0xF, true);
    x = fmaxf(x, __int_as_float(v));
    v = __builtin_amdgcn_update_dpp(0, __float_as_int(x), 0x128, 0xF, 0xF, true);
    x = fmaxf(x, __int_as_float(v));
    return x;
}
__device__ __forceinline__ float dpp_sum16(float x) {
    int v;
    v = __builtin_amdgcn_update_dpp(0, __float_as_int(x), 0xB1, 0xF, 0xF, true);
    x += __int_as_float(v);
    v = __builtin_amdgcn_update_dpp(0, __float_as_int(x), 0x4E, 0xF, 0xF, true);
    x += __int_as_float(v);
    v = __builtin_amdgcn_update_dpp(0, __float_as_int(x), 0x124, 0xF, 0xF, true);
    x += __int_as_float(v);
    v = __builtin_amdgcn_update_dpp(0, __float_as_int(x), 0x128, 0xF, 0xF, true);
    x += __int_as_float(v);
    return x;
}

// ---------------- plain cast fp32 -> bf16 (vector8) ----------------
__global__ __launch_bounds__(256) void cast_bf16(const float* __restrict__ in,
                                                 ushort* __restrict__ out, int n8) {
    int i = blockIdx.x * 256 + threadIdx.x;
    int stride = gridDim.x * 256;
    for (; i < n8; i += stride) {
        float4 a = ((const float4*)in)[2 * i];
        float4 b = ((const float4*)in)[2 * i + 1];
        short8 o;
        o[0] = (short)f2b(a.x); o[1] = (short)f2b(a.y);
        o[2] = (short)f2b(a.z); o[3] = (short)f2b(a.w);
        o[4] = (short)f2b(b.x); o[5] = (short)f2b(b.y);
        o[6] = (short)f2b(b.z); o[7] = (short)f2b(b.w);
        ((short8*)out)[i] = o;
    }
}

// ---------------- W cast+transpose: [48][D][E] fp32 -> [48][E][D] bf16 ----------------
__global__ __launch_bounds__(256) void transpose_w(const float* __restrict__ Wq,
                                                   const float* __restrict__ Wk,
                                                   const float* __restrict__ Wv,
                                                   ushort* __restrict__ wt) {
    int g = blockIdx.y;                 // 0..47 (w*16+h)
    int d0 = blockIdx.x * 64;
    const float* W = (g < 16 ? Wq : (g < 32 ? Wk : Wv)) + (size_t)(g & 15) * (D_ * E_);
    __shared__ __align__(16) ushort T[64 * 80];   // T[e][d-col], pitch 80
    int t = threadIdx.x;
    #pragma unroll
    for (int it = 0; it < 4; ++it) {               // 64 d-rows x 16 float4 cols
        int i = it * 256 + t;
        int r = i >> 4, c = i & 15;
        float4 x = *(const float4*)(W + (size_t)(d0 + r) * E_ + c * 4);
        T[(c * 4 + 0) * 80 + r] = f2b(x.x);
        T[(c * 4 + 1) * 80 + r] = f2b(x.y);
        T[(c * 4 + 2) * 80 + r] = f2b(x.z);
        T[(c * 4 + 3) * 80 + r] = f2b(x.w);
    }
    __syncthreads();
    #pragma unroll
    for (int it = 0; it < 2; ++it) {               // 64 e-rows x 8 chunks of 8
        int i = it * 256 + t;
        int e = i >> 3, c = i & 7;
        short8 x = *(const short8*)&T[e * 80 + c * 8];
        *(short8*)&wt[((size_t)g * E_ + e) * D_ + d0 + c * 8] = x;
    }
}

// ---------------- V transpose: [bh][S][E] -> [bh][E][S] (bf16) ----------------
__global__ __launch_bounds__(256) void transpose_v(const ushort* __restrict__ v,
                                                   ushort* __restrict__ vt) {
    int s0 = blockIdx.x * 64;
    int bh = blockIdx.y;
    __shared__ __align__(16) ushort T[64 * 80];   // T[e][s-col]
    int t = threadIdx.x;
    #pragma unroll
    for (int it = 0; it < 2; ++it) {
        int i = it * 256 + t;
        int r = i >> 3, c = i & 7;                 // s-row r, e-chunk c
        short8 x = *(const short8*)&v[((size_t)bh * S_ + s0 + r) * E_ + c * 8];
        #pragma unroll
        for (int j = 0; j < 8; ++j) T[(c * 8 + j) * 80 + r] = (ushort)x[j];
    }
    __syncthreads();
    #pragma unroll
    for (int it = 0; it < 2; ++it) {
        int i = it * 256 + t;
        int e = i >> 3, c = i & 7;
        short8 x = *(const short8*)&T[e * 80 + c * 8];
        *(short8*)&vt[((size_t)bh * E_ + e) * S_ + s0 + c * 8] = x;
    }
}

// ---------------- QKV GEMM: [8192 x 1024] x [1024 x 64] per (w,h), bf16 MFMA ----------------
__global__ __launch_bounds__(256) void gemm_qkv(const ushort* __restrict__ xb,
                                                const ushort* __restrict__ wt,
                                                ushort* __restrict__ qkv) {
    const int m0 = blockIdx.x * 256;
    const int wh = blockIdx.y;           // 0..47
    const ushort* Wg = wt + (size_t)wh * (E_ * D_);
    ushort* outw = qkv + (size_t)(wh >> 4) * ((size_t)B_ * H_ * S_ * E_);
    const int h = wh & 15;

    __shared__ __align__(16) ushort As[256 * 32];   // [256][32] swizzled
    __shared__ __align__(16) ushort Bs[64 * 32];    // [64][32]  swizzled

    const int t = threadIdx.x, l = t & 63, wid = t >> 6;
    floatx4 acc[4][4] = {};

    for (int k0 = 0; k0 < D_; k0 += 32) {
        __syncthreads();
        #pragma unroll
        for (int it = 0; it < 4; ++it) {            // A: 1024 chunks
            int i = it * 256 + t;
            int r = i >> 2, cs = i & 3;
            int c = cs ^ ((r >> 1) & 3);
            GLD16(xb + (size_t)(m0 + r) * D_ + k0 + c * 8, &As[i * 8]);
        }
        {                                            // B: 256 chunks
            int r = t >> 2, cs = t & 3;
            int c = cs ^ ((r >> 1) & 3);
            GLD16(Wg + (size_t)r * D_ + k0 + c * 8, &Bs[t * 8]);
        }
        __syncthreads();

        short8 af[4], bf[4];
        #pragma unroll
        for (int mf = 0; mf < 4; ++mf) {
            int row = wid * 64 + 16 * mf + (l & 15);
            int c = (l >> 4) ^ ((row >> 1) & 3);
            af[mf] = *(const short8*)&As[row * 32 + c * 8];
        }
        #pragma unroll
        for (int nf = 0; nf < 4; ++nf) {
            int row = 16 * nf + (l & 15);
            int c = (l >> 4) ^ ((row >> 1) & 3);
            bf[nf] = *(const short8*)&Bs[row * 32 + c * 8];
        }
        #pragma unroll
        for (int mf = 0; mf < 4; ++mf)
            #pragma unroll
            for (int nf = 0; nf < 4; ++nf)
                acc[mf][nf] = __builtin_amdgcn_mfma_f32_16x16x32_bf16(af[mf], bf[nf], acc[mf][nf], 0, 0, 0);
    }

    #pragma unroll
    for (int mf = 0; mf < 4; ++mf)
        #pragma unroll
        for (int nf = 0; nf < 4; ++nf)
            #pragma unroll
            for (int r = 0; r < 4; ++r) {
                int m = m0 + wid * 64 + 16 * mf + (l >> 4) * 4 + r;
                int b = m >> 11, s = m & (S_ - 1);
                int e = 16 * nf + (l & 15);
                outw[((size_t)((b << 4) + h) * S_ + s) * E_ + e] = f2b(acc[mf][nf][r]);
            }
}

// ---------------- Flash attention (causal), bf16 MFMA, 2-phase pipelined ----------------
// grid: 1024 1-D blocks. Block n: x = n>>6 (0..15), bh = n&63 (XCD = n%8 = bh%8).
// Balanced pairs {x, 31-x} = 33 KV-tile-units per block. LDS 40 KB (QP overlay).
// Softmax row-reductions moved to DPP (VALU pipe) -- the LDS pipe was the saturated
// resource (~50 DS ops/wave/tile incl. 16 shfl->ds_swizzle); DPP removes 16 of them.
__global__ __launch_bounds__(256) void flash(const ushort* __restrict__ qg,
                                             const ushort* __restrict__ kg,
                                             const ushort* __restrict__ vtg,
                                             ushort* __restrict__ attn) {
    const int n = blockIdx.x;
    const int x = n >> 6;          // 0..15
    const int bh = n & 63;
    const int b = bh >> 4, h = bh & 15;
    const ushort* qb = qg + (size_t)bh * (S_ * E_);
    const ushort* kb = kg + (size_t)bh * (S_ * E_);
    const ushort* vb = vtg + (size_t)bh * (E_ * S_);

    __shared__ __align__(16) ushort QP[64 * 64];      // Q staging [q][e] swizzled, THEN per-wave P
    __shared__ __align__(16) ushort Ks[2][64 * 64];   // [t][e]   swizzled, double-buffered
    __shared__ __align__(16) ushort Vs[2][64 * 64];   // [e][j]   swizzled, double-buffered

    const int t = threadIdx.x, l = t & 63, wid = t >> 6;
    const float SC = 0.18033688f;                  // (1/sqrt(E)) * log2(e)
    const float NEG_INF = -__builtin_inff();
    const int ri_base = wid * 16 + ((l >> 4) << 2);
    const int qts[2] = {x, 31 - x};
    ushort* Pw = &QP[wid * 1024];                  // this wave's 16x64 P quarter

    #pragma unroll 1
    for (int qi = 0; qi < 2; ++qi) {
        const int qt = qts[qi];

        // prologue: stage Q + first K/V tile
        #pragma unroll
        for (int it = 0; it < 2; ++it) {
            int i = it * 256 + t;
            int r = i >> 3, cs = i & 7, c = cs ^ (r & 7);
            GLD16(qb + (size_t)(qt * 64 + r) * E_ + c * 8, &QP[i * 8]);
            GLD16(kb + (size_t)r * E_ + c * 8, &Ks[0][i * 8]);
            GLD16(vb + (size_t)r * S_ + c * 8, &Vs[0][i * 8]);
        }
        __syncthreads();

        short8 qf[2];   // Q fragment lives in registers; QP is dead for Q after this
        #pragma unroll
        for (int ks = 0; ks < 2; ++ks) {
            int row = wid * 16 + (l & 15);
            int c = ((l >> 4) + 4 * ks) ^ (row & 7);
            qf[ks] = *(const short8*)&QP[row * 64 + c * 8];
        }

        floatx4 o[4] = {};
        float mr[4], lr[4];
        #pragma unroll
        for (int r = 0; r < 4; ++r) { mr[r] = NEG_INF; lr[r] = 0.f; }

        int buf = 0;
        for (int jt = 0; jt <= qt; ++jt) {
            // issue next tile's staging BEFORE compute (latency hides under compute)
            if (jt < qt) {
                #pragma unroll
                for (int it = 0; it < 2; ++it) {
                    int i = it * 256 + t;
                    int r = i >> 3, cs = i & 7, c = cs ^ (r & 7);
                    GLD16(kb + (size_t)((jt + 1) * 64 + r) * E_ + c * 8, &Ks[buf ^ 1][i * 8]);
                    GLD16(vb + (size_t)r * S_ + (jt + 1) * 64 + c * 8, &Vs[buf ^ 1][i * 8]);
                }
            }

            // S = Q K^T on current buffer (raw scores)
            floatx4 s[4] = {};
            #pragma unroll
            for (int nf = 0; nf < 4; ++nf) {
                #pragma unroll
                for (int ks = 0; ks < 2; ++ks) {
                    int row = 16 * nf + (l & 15);
                    int c = ((l >> 4) + 4 * ks) ^ (row & 7);
                    short8 kf = *(const short8*)&Ks[buf][row * 64 + c * 8];
                    s[nf] = __builtin_amdgcn_mfma_f32_16x16x32_bf16(qf[ks], kf, s[nf], 0, 0, 0);
                }
            }

            // causal mask on diagonal tile only (raw scores, -inf)
            if (jt == qt) {
                #pragma unroll
                for (int nf = 0; nf < 4; ++nf) {
                    int cj = 16 * nf + (l & 15);
                    #pragma unroll
                    for (int r = 0; r < 4; ++r)
                        if (cj > ri_base + r) s[nf][r] = NEG_INF;
                }
            }

            // row max (DPP, VALU pipe) + defer-max check
            float mxr[4]; bool ok = true;
            #pragma unroll
            for (int r = 0; r < 4; ++r) {
                float mx = fmaxf(fmaxf(s[0][r], s[1][r]), fmaxf(s[2][r], s[3][r]));
                mx = dpp_max16(mx);
                mxr[r] = mx;
                ok = ok && ((mx - mr[r]) * SC <= 8.0f);
            }

            if (!__all(ok)) {   // rescale path (rare after warm-up)
                #pragma unroll
                for (int r = 0; r < 4; ++r) {
                    float mn = fmaxf(mr[r], mxr[r]);
                    float al = fast_exp2((mr[r] - mn) * SC);
                    mr[r] = mn;
                    lr[r] *= al;
                    #pragma unroll
                    for (int nf = 0; nf < 4; ++nf) o[nf][r] *= al;
                }
            }

            // exp2(fma) + lane-partial row sums (no cross-lane here)
            #pragma unroll
            for (int r = 0; r < 4; ++r) {
                float nm = -mr[r] * SC;
                float rs = 0.f;
                #pragma unroll
                for (int nf = 0; nf < 4; ++nf) {
                    float p = fast_exp2(fmaf(s[nf][r], SC, nm));
                    s[nf][r] = p;
                    rs += p;
                }
                lr[r] += rs;
            }

            // P -> wave-private quarter of QP (packed bf16 cvt, swizzled u16 writes)
            #pragma unroll
            for (int nf = 0; nf < 4; ++nf) {
                int col = 16 * nf + (l & 15);
                int sw_hi = (col >> 3) << 3;   // swizzle chunk base, col&7 fixed
                #pragma unroll
                for (int rp = 0; rp < 2; ++rp) {
                    unsigned pk = cvt_pk_bf16(s[nf][2 * rp], s[nf][2 * rp + 1]);
                    int row0 = (l >> 4) * 4 + 2 * rp;
                    int a0 = row0 * 64 + ((sw_hi >> 3) ^ (row0 & 7)) * 8 + (col & 7);
                    int a1 = (row0 + 1) * 64 + ((sw_hi >> 3) ^ ((row0 + 1) & 7)) * 8 + (col & 7);
                    Pw[a0] = (ushort)pk;
                    Pw[a1] = (ushort)(pk >> 16);
                }
            }

            // O += P V
            short8 pf[2];
            #pragma unroll
            for (int ks = 0; ks < 2; ++ks) {
                int row = l & 15;
                int c = ((l >> 4) + 4 * ks) ^ (row & 7);
                pf[ks] = *(const short8*)&Pw[row * 64 + c * 8];
            }
            #pragma unroll
            for (int nf = 0; nf < 4; ++nf) {
                #pragma unroll
                for (int ks = 0; ks < 2; ++ks) {
                    int row = 16 * nf + (l & 15);
                    int c = ((l >> 4) + 4 * ks) ^ (row & 7);
                    short8 vf = *(const short8*)&Vs[buf][row * 64 + c * 8];
                    o[nf] = __builtin_amdgcn_mfma_f32_16x16x32_bf16(pf[ks], vf, o[nf], 0, 0, 0);
                }
            }

            __syncthreads();   // drains this iteration's prefetch (vmcnt) + protects buf^1
            buf ^= 1;
        }

        // epilogue: reduce lane-partial sums (DPP), normalize, bounce via Pw for coalesced writes
        #pragma unroll
        for (int r = 0; r < 4; ++r)
            lr[r] = 1.0f / dpp_sum16(lr[r]);
        #pragma unroll
        for (int nf = 0; nf < 4; ++nf) {
            int col = 16 * nf + (l & 15);
            #pragma unroll
            for (int rp = 0; rp < 2; ++rp) {
                unsigned pk = cvt_pk_bf16(o[nf][2 * rp] * lr[2 * rp],
                                          o[nf][2 * rp + 1] * lr[2 * rp + 1]);
                int row0 = (l >> 4) * 4 + 2 * rp;
                int a0 = row0 * 64 + (((col >> 3)) ^ (row0 & 7)) * 8 + (col & 7);
                int a1 = (row0 + 1) * 64 + (((col >> 3)) ^ ((row0 + 1) & 7)) * 8 + (col & 7);
                Pw[a0] = (ushort)pk;
                Pw[a1] = (ushort)(pk >> 16);
            }
        }
        #pragma unroll
        for (int it = 0; it < 2; ++it) {               // 16 rows x 8 chunks per wave
            int i = it * 64 + l;
            int row = i >> 3, cc = i & 7;
            int c = cc ^ (row & 7);
            short8 vv = *(const short8*)&Pw[row * 64 + c * 8];
            int s_abs = qt * 64 + wid * 16 + row;
            *(short8*)&attn[((size_t)(b * S_ + s_abs)) * D_ + h * E_ + cc * 8] = vv;
        }
        __syncthreads();   // all waves done with QP before next q-tile's Q staging
    }
}

// ---------------- output projection: [8192x1024] x Wp^T + bp, bf16 MFMA, fp32 out ----------------
__global__ __launch_bounds__(256) void out_proj(const ushort* __restrict__ a,
                                                const ushort* __restrict__ wpb,
                                                const float* __restrict__ bp,
                                                float* __restrict__ out) {
    const int m0 = blockIdx.x * 128;
    const int n0 = blockIdx.y * 128;

    __shared__ __align__(16) ushort As[128 * 32];
    __shared__ __align__(16) ushort Bs[128 * 32];

    const int t = threadIdx.x, l = t & 63, wid = t >> 6;
    const int wm = (wid & 1) * 64, wn = (wid >> 1) * 64;
    floatx4 acc[4][4] = {};

    for (int k0 = 0; k0 < D_; k0 += 32) {
        __syncthreads();
        #pragma unroll
        for (int it = 0; it < 2; ++it) {
            int i = it * 256 + t;
            int r = i >> 2, cs = i & 3;
            int c = cs ^ ((r >> 1) & 3);
            GLD16(a + (size_t)(m0 + r) * D_ + k0 + c * 8, &As[i * 8]);
            GLD16(wpb + (size_t)(n0 + r) * D_ + k0 + c * 8, &Bs[i * 8]);
        }
        __syncthreads();

        short8 af[4], bf[4];
        #pragma unroll
        for (int mf = 0; mf < 4; ++mf) {
            int row = wm + 16 * mf + (l & 15);
            int c = (l >> 4) ^ ((row >> 1) & 3);
            af[mf] = *(const short8*)&As[row * 32 + c * 8];
        }
        #pragma unroll
        for (int nf = 0; nf < 4; ++nf) {
            int row = wn + 16 * nf + (l & 15);
            int c = (l >> 4) ^ ((row >> 1) & 3);
            bf[nf] = *(const short8*)&Bs[row * 32 + c * 8];
        }
        #pragma unroll
        for (int mf = 0; mf < 4; ++mf)
            #pragma unroll
            for (int nf = 0; nf < 4; ++nf)
                acc[mf][nf] = __builtin_amdgcn_mfma_f32_16x16x32_bf16(af[mf], bf[nf], acc[mf][nf], 0, 0, 0);
    }

    #pragma unroll
    for (int nf = 0; nf < 4; ++nf) {
        int col = n0 + wn + 16 * nf + (l & 15);
        float bias = bp[col];
        #pragma unroll
        for (int mf = 0; mf < 4; ++mf)
            #pragma unroll
            for (int r = 0; r < 4; ++r) {
                int m = m0 + wm + 16 * mf + (l >> 4) * 4 + r;
                out[(size_t)m * D_ + col] = acc[mf][nf][r] + bias;
            }
    }
}

extern "C" void kernel_launch(void* const* d_in, const int* in_sizes, int n_in,
                              void* d_out, int out_size, void* d_ws, size_t ws_size,
                              hipStream_t stream) {
    const float* x  = (const float*)d_in[0];
    const float* Wq = (const float*)d_in[1];
    const float* Wk = (const float*)d_in[2];
    const float* Wv = (const float*)d_in[3];
    const float* Wp = (const float*)d_in[4];
    const float* bp = (const float*)d_in[5];

    ushort* ws = (ushort*)d_ws;
    const size_t NX  = (size_t)M_ * D_;          // 8M
    const size_t NW  = (size_t)48 * E_ * D_;     // 3.15M
    const size_t NP  = (size_t)D_ * D_;          // 1M
    const size_t QSZ = (size_t)B_ * H_ * S_ * E_;// 8M
    ushort* xb    = ws;
    ushort* wt    = xb + NX;
    ushort* wpb   = wt + NW;
    ushort* qkvb  = wpb + NP;        // q | k | v
    ushort* vt    = qkvb + 3 * QSZ;
    ushort* attnb = vt + QSZ;        // total ~104 MB

    cast_bf16  <<<2048, 256, 0, stream>>>(x, xb, (int)(NX / 8));
    cast_bf16  <<<512, 256, 0, stream>>>(Wp, wpb, (int)(NP / 8));
    transpose_w<<<dim3(16, 48), 256, 0, stream>>>(Wq, Wk, Wv, wt);
    gemm_qkv   <<<dim3(M_ / 256, 48), 256, 0, stream>>>(xb, wt, qkvb);
    transpose_v<<<dim3(S_ / 64, B_ * H_), 256, 0, stream>>>(qkvb + 2 * QSZ, vt);
    flash      <<<1024, 256, 0, stream>>>(qkvb, qkvb + QSZ, vt, attnb);
    out_proj   <<<dim3(M_ / 128, D_ / 128), 256, 0, stream>>>(attnb, wpb, bp, (float*)d_out);
}

// Round 12
// 196.220 us; speedup vs baseline: 1.1546x; 1.0699x over previous
//
#include <hip/hip_runtime.h>

#define B_ 4
#define S_ 2048
#define D_ 1024
#define H_ 16
#define E_ 64
#define M_ (B_*S_)   // 8192

typedef __attribute__((ext_vector_type(8))) short short8;   // 8 bf16 = 4 VGPRs (MFMA A/B frag)
typedef __attribute__((ext_vector_type(4))) float floatx4;  // MFMA C/D frag

// async global->LDS, 16B per lane; dest must be linear (wave base + lane*16)
#define GLD16(g, l) __builtin_amdgcn_global_load_lds( \
    (const __attribute__((address_space(1))) unsigned*)(g), \
    (__attribute__((address_space(3))) unsigned*)(l), 16, 0, 0)

__device__ __forceinline__ ushort f2b(float f) {   // fp32 -> bf16 RNE
    union { float f; unsigned u; } v; v.f = f;
    unsigned r = v.u + 0x7fffu + ((v.u >> 16) & 1u);
    return (ushort)(r >> 16);
}
__device__ __forceinline__ unsigned cvt_pk_bf16(float lo, float hi) {  // 2xf32 -> packed bf16x2
    unsigned r;
    asm("v_cvt_pk_bf16_f32 %0, %1, %2" : "=v"(r) : "v"(lo), "v"(hi));
    return r;
}
__device__ __forceinline__ float fast_exp2(float x) {
#if __has_builtin(__builtin_amdgcn_exp2f)
    return __builtin_amdgcn_exp2f(x);
#else
    float r; asm("v_exp_f32 %0, %1" : "=v"(r) : "v"(x)); return r;
#endif
}
__device__ __forceinline__ float lane_pull(float v, int srclane) {  // pull v from lane srclane
    return __int_as_float(__builtin_amdgcn_ds_bpermute(srclane << 2, __float_as_int(v)));
}

// ---------------- plain cast fp32 -> bf16 (vector8) ----------------
__global__ __launch_bounds__(256) void cast_bf16(const float* __restrict__ in,
                                                 ushort* __restrict__ out, int n8) {
    int i = blockIdx.x * 256 + threadIdx.x;
    int stride = gridDim.x * 256;
    for (; i < n8; i += stride) {
        float4 a = ((const float4*)in)[2 * i];
        float4 b = ((const float4*)in)[2 * i + 1];
        short8 o;
        o[0] = (short)f2b(a.x); o[1] = (short)f2b(a.y);
        o[2] = (short)f2b(a.z); o[3] = (short)f2b(a.w);
        o[4] = (short)f2b(b.x); o[5] = (short)f2b(b.y);
        o[6] = (short)f2b(b.z); o[7] = (short)f2b(b.w);
        ((short8*)out)[i] = o;
    }
}

// ---------------- W cast+transpose: [48][D][E] fp32 -> [48][E][D] bf16 ----------------
__global__ __launch_bounds__(256) void transpose_w(const float* __restrict__ Wq,
                                                   const float* __restrict__ Wk,
                                                   const float* __restrict__ Wv,
                                                   ushort* __restrict__ wt) {
    int g = blockIdx.y;                 // 0..47 (w*16+h)
    int d0 = blockIdx.x * 64;
    const float* W = (g < 16 ? Wq : (g < 32 ? Wk : Wv)) + (size_t)(g & 15) * (D_ * E_);
    __shared__ __align__(16) ushort T[64 * 80];   // T[e][d-col], pitch 80
    int t = threadIdx.x;
    #pragma unroll
    for (int it = 0; it < 4; ++it) {               // 64 d-rows x 16 float4 cols
        int i = it * 256 + t;
        int r = i >> 4, c = i & 15;
        float4 x = *(const float4*)(W + (size_t)(d0 + r) * E_ + c * 4);
        T[(c * 4 + 0) * 80 + r] = f2b(x.x);
        T[(c * 4 + 1) * 80 + r] = f2b(x.y);
        T[(c * 4 + 2) * 80 + r] = f2b(x.z);
        T[(c * 4 + 3) * 80 + r] = f2b(x.w);
    }
    __syncthreads();
    #pragma unroll
    for (int it = 0; it < 2; ++it) {               // 64 e-rows x 8 chunks of 8
        int i = it * 256 + t;
        int e = i >> 3, c = i & 7;
        short8 x = *(const short8*)&T[e * 80 + c * 8];
        *(short8*)&wt[((size_t)g * E_ + e) * D_ + d0 + c * 8] = x;
    }
}

// ---------------- V transpose: [bh][S][E] -> [bh][E][S] (bf16) ----------------
__global__ __launch_bounds__(256) void transpose_v(const ushort* __restrict__ v,
                                                   ushort* __restrict__ vt) {
    int s0 = blockIdx.x * 64;
    int bh = blockIdx.y;
    __shared__ __align__(16) ushort T[64 * 80];   // T[e][s-col]
    int t = threadIdx.x;
    #pragma unroll
    for (int it = 0; it < 2; ++it) {
        int i = it * 256 + t;
        int r = i >> 3, c = i & 7;                 // s-row r, e-chunk c
        short8 x = *(const short8*)&v[((size_t)bh * S_ + s0 + r) * E_ + c * 8];
        #pragma unroll
        for (int j = 0; j < 8; ++j) T[(c * 8 + j) * 80 + r] = (ushort)x[j];
    }
    __syncthreads();
    #pragma unroll
    for (int it = 0; it < 2; ++it) {
        int i = it * 256 + t;
        int e = i >> 3, c = i & 7;
        short8 x = *(const short8*)&T[e * 80 + c * 8];
        *(short8*)&vt[((size_t)bh * E_ + e) * S_ + s0 + c * 8] = x;
    }
}

// ---------------- QKV GEMM: [8192 x 1024] x [1024 x 64] per (w,h), bf16 MFMA ----------------
__global__ __launch_bounds__(256) void gemm_qkv(const ushort* __restrict__ xb,
                                                const ushort* __restrict__ wt,
                                                ushort* __restrict__ qkv) {
    const int m0 = blockIdx.x * 256;
    const int wh = blockIdx.y;           // 0..47
    const ushort* Wg = wt + (size_t)wh * (E_ * D_);
    ushort* outw = qkv + (size_t)(wh >> 4) * ((size_t)B_ * H_ * S_ * E_);
    const int h = wh & 15;

    __shared__ __align__(16) ushort As[256 * 32];   // [256][32] swizzled
    __shared__ __align__(16) ushort Bs[64 * 32];    // [64][32]  swizzled

    const int t = threadIdx.x, l = t & 63, wid = t >> 6;
    floatx4 acc[4][4] = {};

    for (int k0 = 0; k0 < D_; k0 += 32) {
        __syncthreads();
        #pragma unroll
        for (int it = 0; it < 4; ++it) {            // A: 1024 chunks
            int i = it * 256 + t;
            int r = i >> 2, cs = i & 3;
            int c = cs ^ ((r >> 1) & 3);
            GLD16(xb + (size_t)(m0 + r) * D_ + k0 + c * 8, &As[i * 8]);
        }
        {                                            // B: 256 chunks
            int r = t >> 2, cs = t & 3;
            int c = cs ^ ((r >> 1) & 3);
            GLD16(Wg + (size_t)r * D_ + k0 + c * 8, &Bs[t * 8]);
        }
        __syncthreads();

        short8 af[4], bf[4];
        #pragma unroll
        for (int mf = 0; mf < 4; ++mf) {
            int row = wid * 64 + 16 * mf + (l & 15);
            int c = (l >> 4) ^ ((row >> 1) & 3);
            af[mf] = *(const short8*)&As[row * 32 + c * 8];
        }
        #pragma unroll
        for (int nf = 0; nf < 4; ++nf) {
            int row = 16 * nf + (l & 15);
            int c = (l >> 4) ^ ((row >> 1) & 3);
            bf[nf] = *(const short8*)&Bs[row * 32 + c * 8];
        }
        #pragma unroll
        for (int mf = 0; mf < 4; ++mf)
            #pragma unroll
            for (int nf = 0; nf < 4; ++nf)
                acc[mf][nf] = __builtin_amdgcn_mfma_f32_16x16x32_bf16(af[mf], bf[nf], acc[mf][nf], 0, 0, 0);
    }

    #pragma unroll
    for (int mf = 0; mf < 4; ++mf)
        #pragma unroll
        for (int nf = 0; nf < 4; ++nf)
            #pragma unroll
            for (int r = 0; r < 4; ++r) {
                int m = m0 + wid * 64 + 16 * mf + (l >> 4) * 4 + r;
                int b = m >> 11, s = m & (S_ - 1);
                int e = 16 * nf + (l & 15);
                outw[((size_t)((b << 4) + h) * S_ + s) * E_ + e] = f2b(acc[mf][nf][r]);
            }
}

// ---------------- Flash attention (causal), bf16 MFMA, swapped QK^T ----------------
// grid: 1024 1-D blocks. Block n: x = n>>6 (0..15), bh = n&63 (XCD = n%8 = bh%8).
// Balanced pairs {x, 31-x} = 33 KV-tile-units per block. LDS 40 KB (QP overlay).
// SWAPPED QK^T: mfma(K,Q) -> lane owns ONE q-row (q-local = l&15) with kv=16nf+4(l>>4)+r.
// Softmax is 15 in-lane fmax + 2 shfl; P packs 4 contig kv -> ONE ds_write_b64 per nf
// (4 vs 16 LDS writes/tile). Written P layout is bit-identical to the previous [q][kv]
// swizzled format, so the P-read / PV / epilogue are unchanged.
__global__ __launch_bounds__(256) void flash(const ushort* __restrict__ qg,
                                             const ushort* __restrict__ kg,
                                             const ushort* __restrict__ vtg,
                                             ushort* __restrict__ attn) {
    const int n = blockIdx.x;
    const int x = n >> 6;          // 0..15
    const int bh = n & 63;
    const int b = bh >> 4, h = bh & 15;
    const ushort* qb = qg + (size_t)bh * (S_ * E_);
    const ushort* kb = kg + (size_t)bh * (S_ * E_);
    const ushort* vb = vtg + (size_t)bh * (E_ * S_);

    __shared__ __align__(16) ushort QP[64 * 64];      // Q staging [q][e] swizzled, THEN per-wave P
    __shared__ __align__(16) ushort Ks[2][64 * 64];   // [t][e]   swizzled, double-buffered
    __shared__ __align__(16) ushort Vs[2][64 * 64];   // [e][j]   swizzled, double-buffered

    const int t = threadIdx.x, l = t & 63, wid = t >> 6;
    const float SC = 0.18033688f;                  // (1/sqrt(E)) * log2(e)
    const float NEG_INF = -__builtin_inff();
    const int g = l >> 4;                          // kv-lane-group 0..3
    const int qloc = l & 15;                       // this lane's q-row (wave-local)
    const int qts[2] = {x, 31 - x};
    ushort* Pw = &QP[wid * 1024];                  // this wave's 16x64 P quarter

    #pragma unroll 1
    for (int qi = 0; qi < 2; ++qi) {
        const int qt = qts[qi];

        // prologue: stage Q + first K/V tile
        #pragma unroll
        for (int it = 0; it < 2; ++it) {
            int i = it * 256 + t;
            int r = i >> 3, cs = i & 7, c = cs ^ (r & 7);
            GLD16(qb + (size_t)(qt * 64 + r) * E_ + c * 8, &QP[i * 8]);
            GLD16(kb + (size_t)r * E_ + c * 8, &Ks[0][i * 8]);
            GLD16(vb + (size_t)r * S_ + c * 8, &Vs[0][i * 8]);
        }
        __syncthreads();

        short8 qf[2];   // Q fragment lives in registers; QP is dead for Q after this
        #pragma unroll
        for (int ks = 0; ks < 2; ++ks) {
            int row = wid * 16 + qloc;
            int c = (g + 4 * ks) ^ (row & 7);
            qf[ks] = *(const short8*)&QP[row * 64 + c * 8];
        }

        floatx4 o[4] = {};
        float mr = NEG_INF, lr = 0.f;

        int buf = 0;
        for (int jt = 0; jt <= qt; ++jt) {
            // issue next tile's staging BEFORE compute (latency hides under compute)
            if (jt < qt) {
                #pragma unroll
                for (int it = 0; it < 2; ++it) {
                    int i = it * 256 + t;
                    int r = i >> 3, cs = i & 7, c = cs ^ (r & 7);
                    GLD16(kb + (size_t)((jt + 1) * 64 + r) * E_ + c * 8, &Ks[buf ^ 1][i * 8]);
                    GLD16(vb + (size_t)r * S_ + (jt + 1) * 64 + c * 8, &Vs[buf ^ 1][i * 8]);
                }
            }

            // S = Q K^T, SWAPPED operands: s[nf][r] = S[q = wid*16+qloc][kv = 16nf+4g+r]
            floatx4 s[4] = {};
            #pragma unroll
            for (int nf = 0; nf < 4; ++nf) {
                #pragma unroll
                for (int ks = 0; ks < 2; ++ks) {
                    int row = 16 * nf + qloc;
                    int c = (g + 4 * ks) ^ (row & 7);
                    short8 kf = *(const short8*)&Ks[buf][row * 64 + c * 8];
                    s[nf] = __builtin_amdgcn_mfma_f32_16x16x32_bf16(kf, qf[ks], s[nf], 0, 0, 0);
                }
            }

            // causal mask on diagonal tile only (raw scores, -inf); kv > q within tile
            if (jt == qt) {
                int qrow = wid * 16 + qloc;
                #pragma unroll
                for (int nf = 0; nf < 4; ++nf)
                    #pragma unroll
                    for (int r = 0; r < 4; ++r)
                        if (16 * nf + 4 * g + r > qrow) s[nf][r] = NEG_INF;
            }

            // row max: 15 in-lane fmax + 2 cross-lane (xor16, xor32); defer-max check
            float mx = s[0][0];
            #pragma unroll
            for (int nf = 0; nf < 4; ++nf)
                #pragma unroll
                for (int r = 0; r < 4; ++r) mx = fmaxf(mx, s[nf][r]);
            mx = fmaxf(mx, __shfl_xor(mx, 16));
            mx = fmaxf(mx, __shfl_xor(mx, 32));
            bool ok = (mx - mr) * SC <= 8.0f;

            if (!__all(ok)) {   // rescale path (rare after warm-up)
                float mn = fmaxf(mr, mx);
                float al = fast_exp2((mr - mn) * SC);
                mr = mn;
                lr *= al;
                #pragma unroll
                for (int r = 0; r < 4; ++r) {      // o rows are q-local 4g+r -> pull their alpha
                    float alq = lane_pull(al, 4 * g + r);
                    #pragma unroll
                    for (int nf = 0; nf < 4; ++nf) o[nf][r] *= alq;
                }
            }

            // exp2(fma) + lane-partial row sum (fully lane-local)
            {
                float nm = -mr * SC;
                float rs = 0.f;
                #pragma unroll
                for (int nf = 0; nf < 4; ++nf)
                    #pragma unroll
                    for (int r = 0; r < 4; ++r) {
                        float p = fast_exp2(fmaf(s[nf][r], SC, nm));
                        s[nf][r] = p;
                        rs += p;
                    }
                lr += rs;
            }

            // P -> wave-private quarter: 4 contiguous kv per nf -> ONE b64 write
            #pragma unroll
            for (int nf = 0; nf < 4; ++nf) {
                unsigned pk0 = cvt_pk_bf16(s[nf][0], s[nf][1]);
                unsigned pk1 = cvt_pk_bf16(s[nf][2], s[nf][3]);
                int chunk = 2 * nf + (g >> 1);
                int sw = chunk ^ (qloc & 7);
                int a = qloc * 64 + sw * 8 + 4 * (g & 1);
                *(uint2*)&Pw[a] = make_uint2(pk0, pk1);
            }

            // O += P V (unchanged: A-frag read matches the written [q][kv] layout)
            short8 pf[2];
            #pragma unroll
            for (int ks = 0; ks < 2; ++ks) {
                int row = l & 15;
                int c = (g + 4 * ks) ^ (row & 7);
                pf[ks] = *(const short8*)&Pw[row * 64 + c * 8];
            }
            #pragma unroll
            for (int nf = 0; nf < 4; ++nf) {
                #pragma unroll
                for (int ks = 0; ks < 2; ++ks) {
                    int row = 16 * nf + (l & 15);
                    int c = (g + 4 * ks) ^ (row & 7);
                    short8 vf = *(const short8*)&Vs[buf][row * 64 + c * 8];
                    o[nf] = __builtin_amdgcn_mfma_f32_16x16x32_bf16(pf[ks], vf, o[nf], 0, 0, 0);
                }
            }

            __syncthreads();   // drains this iteration's prefetch (vmcnt) + protects buf^1
            buf ^= 1;
        }

        // epilogue: complete row sums (xor16+xor32), distribute 1/l to o-rows, write out
        lr += __shfl_xor(lr, 16);
        lr += __shfl_xor(lr, 32);
        float inv = 1.0f / lr;
        float il[4];
        #pragma unroll
        for (int r = 0; r < 4; ++r) il[r] = lane_pull(inv, 4 * g + r);

        #pragma unroll
        for (int nf = 0; nf < 4; ++nf) {
            int col = 16 * nf + qloc;
            #pragma unroll
            for (int rp = 0; rp < 2; ++rp) {
                unsigned pk = cvt_pk_bf16(o[nf][2 * rp] * il[2 * rp],
                                          o[nf][2 * rp + 1] * il[2 * rp + 1]);
                int row0 = g * 4 + 2 * rp;
                int a0 = row0 * 64 + (((col >> 3)) ^ (row0 & 7)) * 8 + (col & 7);
                int a1 = (row0 + 1) * 64 + (((col >> 3)) ^ ((row0 + 1) & 7)) * 8 + (col & 7);
                Pw[a0] = (ushort)pk;
                Pw[a1] = (ushort)(pk >> 16);
            }
        }
        #pragma unroll
        for (int it = 0; it < 2; ++it) {               // 16 rows x 8 chunks per wave
            int i = it * 64 + l;
            int row = i >> 3, cc = i & 7;
            int c = cc ^ (row & 7);
            short8 vv = *(const short8*)&Pw[row * 64 + c * 8];
            int s_abs = qt * 64 + wid * 16 + row;
            *(short8*)&attn[((size_t)(b * S_ + s_abs)) * D_ + h * E_ + cc * 8] = vv;
        }
        __syncthreads();   // all waves done with QP before next q-tile's Q staging
    }
}

// ---------------- output projection: [8192x1024] x Wp^T + bp, bf16 MFMA, fp32 out ----------------
__global__ __launch_bounds__(256) void out_proj(const ushort* __restrict__ a,
                                                const ushort* __restrict__ wpb,
                                                const float* __restrict__ bp,
                                                float* __restrict__ out) {
    const int m0 = blockIdx.x * 128;
    const int n0 = blockIdx.y * 128;

    __shared__ __align__(16) ushort As[128 * 32];
    __shared__ __align__(16) ushort Bs[128 * 32];

    const int t = threadIdx.x, l = t & 63, wid = t >> 6;
    const int wm = (wid & 1) * 64, wn = (wid >> 1) * 64;
    floatx4 acc[4][4] = {};

    for (int k0 = 0; k0 < D_; k0 += 32) {
        __syncthreads();
        #pragma unroll
        for (int it = 0; it < 2; ++it) {
            int i = it * 256 + t;
            int r = i >> 2, cs = i & 3;
            int c = cs ^ ((r >> 1) & 3);
            GLD16(a + (size_t)(m0 + r) * D_ + k0 + c * 8, &As[i * 8]);
            GLD16(wpb + (size_t)(n0 + r) * D_ + k0 + c * 8, &Bs[i * 8]);
        }
        __syncthreads();

        short8 af[4], bf[4];
        #pragma unroll
        for (int mf = 0; mf < 4; ++mf) {
            int row = wm + 16 * mf + (l & 15);
            int c = (l >> 4) ^ ((row >> 1) & 3);
            af[mf] = *(const short8*)&As[row * 32 + c * 8];
        }
        #pragma unroll
        for (int nf = 0; nf < 4; ++nf) {
            int row = wn + 16 * nf + (l & 15);
            int c = (l >> 4) ^ ((row >> 1) & 3);
            bf[nf] = *(const short8*)&Bs[row * 32 + c * 8];
        }
        #pragma unroll
        for (int mf = 0; mf < 4; ++mf)
            #pragma unroll
            for (int nf = 0; nf < 4; ++nf)
                acc[mf][nf] = __builtin_amdgcn_mfma_f32_16x16x32_bf16(af[mf], bf[nf], acc[mf][nf], 0, 0, 0);
    }

    #pragma unroll
    for (int nf = 0; nf < 4; ++nf) {
        int col = n0 + wn + 16 * nf + (l & 15);
        float bias = bp[col];
        #pragma unroll
        for (int mf = 0; mf < 4; ++mf)
            #pragma unroll
            for (int r = 0; r < 4; ++r) {
                int m = m0 + wm + 16 * mf + (l >> 4) * 4 + r;
                out[(size_t)m * D_ + col] = acc[mf][nf][r] + bias;
            }
    }
}

extern "C" void kernel_launch(void* const* d_in, const int* in_sizes, int n_in,
                              void* d_out, int out_size, void* d_ws, size_t ws_size,
                              hipStream_t stream) {
    const float* x  = (const float*)d_in[0];
    const float* Wq = (const float*)d_in[1];
    const float* Wk = (const float*)d_in[2];
    const float* Wv = (const float*)d_in[3];
    const float* Wp = (const float*)d_in[4];
    const float* bp = (const float*)d_in[5];

    ushort* ws = (ushort*)d_ws;
    const size_t NX  = (size_t)M_ * D_;          // 8M
    const size_t NW  = (size_t)48 * E_ * D_;     // 3.15M
    const size_t NP  = (size_t)D_ * D_;          // 1M
    const size_t QSZ = (size_t)B_ * H_ * S_ * E_;// 8M
    ushort* xb    = ws;
    ushort* wt    = xb + NX;
    ushort* wpb   = wt + NW;
    ushort* qkvb  = wpb + NP;        // q | k | v
    ushort* vt    = qkvb + 3 * QSZ;
    ushort* attnb = vt + QSZ;        // total ~104 MB

    cast_bf16  <<<2048, 256, 0, stream>>>(x, xb, (int)(NX / 8));
    cast_bf16  <<<512, 256, 0, stream>>>(Wp, wpb, (int)(NP / 8));
    transpose_w<<<dim3(16, 48), 256, 0, stream>>>(Wq, Wk, Wv, wt);
    gemm_qkv   <<<dim3(M_ / 256, 48), 256, 0, stream>>>(xb, wt, qkvb);
    transpose_v<<<dim3(S_ / 64, B_ * H_), 256, 0, stream>>>(qkvb + 2 * QSZ, vt);
    flash      <<<1024, 256, 0, stream>>>(qkvb, qkvb + QSZ, vt, attnb);
    out_proj   <<<dim3(M_ / 128, D_ / 128), 256, 0, stream>>>(attnb, wpb, bp, (float*)d_out);
}

// Round 14
// 185.076 us; speedup vs baseline: 1.2241x; 1.0602x over previous
//
#include <hip/hip_runtime.h>

#define B_ 4
#define S_ 2048
#define D_ 1024
#define H_ 16
#define E_ 64
#define M_ (B_*S_)   // 8192

typedef __attribute__((ext_vector_type(8))) short short8;   // 8 bf16 = 4 VGPRs (MFMA A/B frag)
typedef __attribute__((ext_vector_type(4))) float floatx4;  // MFMA C/D frag

// async global->LDS, 16B per lane; dest must be linear (wave base + lane*16)
#define GLD16(g, l) __builtin_amdgcn_global_load_lds( \
    (const __attribute__((address_space(1))) unsigned*)(g), \
    (__attribute__((address_space(3))) unsigned*)(l), 16, 0, 0)

__device__ __forceinline__ ushort f2b(float f) {   // fp32 -> bf16 RNE
    union { float f; unsigned u; } v; v.f = f;
    unsigned r = v.u + 0x7fffu + ((v.u >> 16) & 1u);
    return (ushort)(r >> 16);
}
__device__ __forceinline__ unsigned cvt_pk_bf16(float lo, float hi) {  // 2xf32 -> packed bf16x2
    unsigned r;
    asm("v_cvt_pk_bf16_f32 %0, %1, %2" : "=v"(r) : "v"(lo), "v"(hi));
    return r;
}
__device__ __forceinline__ float fast_exp2(float x) {
#if __has_builtin(__builtin_amdgcn_exp2f)
    return __builtin_amdgcn_exp2f(x);
#else
    float r; asm("v_exp_f32 %0, %1" : "=v"(r) : "v"(x)); return r;
#endif
}
__device__ __forceinline__ float lane_pull(float v, int srclane) {  // pull v from lane srclane
    return __int_as_float(__builtin_amdgcn_ds_bpermute(srclane << 2, __float_as_int(v)));
}

// ---------------- plain cast fp32 -> bf16 (vector8) ----------------
__global__ __launch_bounds__(256) void cast_bf16(const float* __restrict__ in,
                                                 ushort* __restrict__ out, int n8) {
    int i = blockIdx.x * 256 + threadIdx.x;
    int stride = gridDim.x * 256;
    for (; i < n8; i += stride) {
        float4 a = ((const float4*)in)[2 * i];
        float4 b = ((const float4*)in)[2 * i + 1];
        short8 o;
        o[0] = (short)f2b(a.x); o[1] = (short)f2b(a.y);
        o[2] = (short)f2b(a.z); o[3] = (short)f2b(a.w);
        o[4] = (short)f2b(b.x); o[5] = (short)f2b(b.y);
        o[6] = (short)f2b(b.z); o[7] = (short)f2b(b.w);
        ((short8*)out)[i] = o;
    }
}

// ---------------- W cast+transpose: [48][D][E] fp32 -> [48][E][D] bf16 ----------------
__global__ __launch_bounds__(256) void transpose_w(const float* __restrict__ Wq,
                                                   const float* __restrict__ Wk,
                                                   const float* __restrict__ Wv,
                                                   ushort* __restrict__ wt) {
    int g = blockIdx.y;                 // 0..47 (w*16+h)
    int d0 = blockIdx.x * 64;
    const float* W = (g < 16 ? Wq : (g < 32 ? Wk : Wv)) + (size_t)(g & 15) * (D_ * E_);
    __shared__ __align__(16) ushort T[64 * 80];   // T[e][d-col], pitch 80
    int t = threadIdx.x;
    #pragma unroll
    for (int it = 0; it < 4; ++it) {               // 64 d-rows x 16 float4 cols
        int i = it * 256 + t;
        int r = i >> 4, c = i & 15;
        float4 x = *(const float4*)(W + (size_t)(d0 + r) * E_ + c * 4);
        T[(c * 4 + 0) * 80 + r] = f2b(x.x);
        T[(c * 4 + 1) * 80 + r] = f2b(x.y);
        T[(c * 4 + 2) * 80 + r] = f2b(x.z);
        T[(c * 4 + 3) * 80 + r] = f2b(x.w);
    }
    __syncthreads();
    #pragma unroll
    for (int it = 0; it < 2; ++it) {               // 64 e-rows x 8 chunks of 8
        int i = it * 256 + t;
        int e = i >> 3, c = i & 7;
        short8 x = *(const short8*)&T[e * 80 + c * 8];
        *(short8*)&wt[((size_t)g * E_ + e) * D_ + d0 + c * 8] = x;
    }
}

// ---------------- QKV GEMM: [8192 x 1024] @ [1024 x 3072] (concat W), bf16 MFMA -------
// grid (32, 24), 512 threads. Tile 256(M) x 128(N): 2 heads per block (same w).
// 8 waves as 4Mx2N, each the proven 64x64 / acc[4][4] shape. Staging: 3 GLD16/thread/step.
// w==2 (V) blocks write TRANSPOSED [bh][e][s] directly (4 consecutive s per frag -> uint2),
// eliminating the separate transpose_v kernel.
__global__ __launch_bounds__(512) void gemm_qkv(const ushort* __restrict__ xb,
                                                const ushort* __restrict__ wt,
                                                ushort* __restrict__ qk,
                                                ushort* __restrict__ vt) {
    const int m0 = blockIdx.x * 256;
    const int n0 = blockIdx.y * 128;
    const int w  = n0 >> 10;             // 0:q 1:k 2:v (block-uniform)

    __shared__ __align__(16) ushort As[256 * 32];   // [256][32] swizzled
    __shared__ __align__(16) ushort Bs[128 * 32];   // [128][32] swizzled

    const int t = threadIdx.x, l = t & 63, wid = t >> 6;
    const int wm = (wid & 3) * 64, wn = (wid >> 2) * 64;
    floatx4 acc[4][4] = {};

    for (int k0 = 0; k0 < D_; k0 += 32) {
        __syncthreads();
        #pragma unroll
        for (int it = 0; it < 2; ++it) {            // A: 1024 chunks / 512 thr
            int i = it * 512 + t;
            int r = i >> 2, cs = i & 3;
            int c = cs ^ ((r >> 1) & 3);
            GLD16(xb + (size_t)(m0 + r) * D_ + k0 + c * 8, &As[i * 8]);
        }
        {                                            // B: 512 chunks / 512 thr
            int r = t >> 2, cs = t & 3;
            int c = cs ^ ((r >> 1) & 3);
            GLD16(wt + (size_t)(n0 + r) * D_ + k0 + c * 8, &Bs[t * 8]);
        }
        __syncthreads();

        short8 af[4], bf[4];
        #pragma unroll
        for (int mf = 0; mf < 4; ++mf) {
            int row = wm + 16 * mf + (l & 15);
            int c = (l >> 4) ^ ((row >> 1) & 3);
            af[mf] = *(const short8*)&As[row * 32 + c * 8];
        }
        #pragma unroll
        for (int nf = 0; nf < 4; ++nf) {
            int row = wn + 16 * nf + (l & 15);
            int c = (l >> 4) ^ ((row >> 1) & 3);
            bf[nf] = *(const short8*)&Bs[row * 32 + c * 8];
        }
        #pragma unroll
        for (int mf = 0; mf < 4; ++mf)
            #pragma unroll
            for (int nf = 0; nf < 4; ++nf)
                acc[mf][nf] = __builtin_amdgcn_mfma_f32_16x16x32_bf16(af[mf], bf[nf], acc[mf][nf], 0, 0, 0);
    }

    if (w < 2) {
        // q/k: [b,h,s,e] bf16 scatter (as before)
        ushort* outw = qk + (size_t)w * ((size_t)B_ * H_ * S_ * E_);
        #pragma unroll
        for (int mf = 0; mf < 4; ++mf)
            #pragma unroll
            for (int nf = 0; nf < 4; ++nf) {
                int n = n0 + wn + 16 * nf + (l & 15);
                int h = (n >> 6) & 15, e = n & 63;
                #pragma unroll
                for (int r = 0; r < 4; ++r) {
                    int m = m0 + wm + 16 * mf + (l >> 4) * 4 + r;
                    int b = m >> 11, s = m & (S_ - 1);
                    outw[((size_t)((b << 4) + h) * S_ + s) * E_ + e] = f2b(acc[mf][nf][r]);
                }
            }
    } else {
        // v: write TRANSPOSED [bh][e][s]; r = 4 consecutive s -> one 8B packed write
        #pragma unroll
        for (int mf = 0; mf < 4; ++mf) {
            int m = m0 + wm + 16 * mf + (l >> 4) * 4;
            int b = m >> 11, s = m & (S_ - 1);
            #pragma unroll
            for (int nf = 0; nf < 4; ++nf) {
                int n = n0 + wn + 16 * nf + (l & 15);
                int h = (n >> 6) & 15, e = n & 63;
                unsigned pk0 = cvt_pk_bf16(acc[mf][nf][0], acc[mf][nf][1]);
                unsigned pk1 = cvt_pk_bf16(acc[mf][nf][2], acc[mf][nf][3]);
                *(uint2*)&vt[((size_t)((b << 4) + h) * E_ + e) * S_ + s] = make_uint2(pk0, pk1);
            }
        }
    }
}

// ---------------- Flash attention (causal), bf16 MFMA, swapped QK^T ----------------
// grid: 1024 1-D blocks. Block n: x = n>>6 (0..15), bh = n&63 (XCD = n%8 = bh%8).
// Balanced pairs {x, 31-x} = 33 KV-tile-units per block. LDS 40 KB (QP overlay).
// SWAPPED QK^T: mfma(K,Q) -> lane owns ONE q-row (q-local = l&15) with kv=16nf+4(l>>4)+r.
// Softmax is 15 in-lane fmax + 2 shfl; P packs 4 contig kv -> ONE ds_write_b64 per nf.
__global__ __launch_bounds__(256) void flash(const ushort* __restrict__ qg,
                                             const ushort* __restrict__ kg,
                                             const ushort* __restrict__ vtg,
                                             ushort* __restrict__ attn) {
    const int n = blockIdx.x;
    const int x = n >> 6;          // 0..15
    const int bh = n & 63;
    const int b = bh >> 4, h = bh & 15;
    const ushort* qb = qg + (size_t)bh * (S_ * E_);
    const ushort* kb = kg + (size_t)bh * (S_ * E_);
    const ushort* vb = vtg + (size_t)bh * (E_ * S_);

    __shared__ __align__(16) ushort QP[64 * 64];      // Q staging [q][e] swizzled, THEN per-wave P
    __shared__ __align__(16) ushort Ks[2][64 * 64];   // [t][e]   swizzled, double-buffered
    __shared__ __align__(16) ushort Vs[2][64 * 64];   // [e][j]   swizzled, double-buffered

    const int t = threadIdx.x, l = t & 63, wid = t >> 6;
    const float SC = 0.18033688f;                  // (1/sqrt(E)) * log2(e)
    const float NEG_INF = -__builtin_inff();
    const int g = l >> 4;                          // kv-lane-group 0..3
    const int qloc = l & 15;                       // this lane's q-row (wave-local)
    const int qts[2] = {x, 31 - x};
    ushort* Pw = &QP[wid * 1024];                  // this wave's 16x64 P quarter

    #pragma unroll 1
    for (int qi = 0; qi < 2; ++qi) {
        const int qt = qts[qi];

        // prologue: stage Q + first K/V tile
        #pragma unroll
        for (int it = 0; it < 2; ++it) {
            int i = it * 256 + t;
            int r = i >> 3, cs = i & 7, c = cs ^ (r & 7);
            GLD16(qb + (size_t)(qt * 64 + r) * E_ + c * 8, &QP[i * 8]);
            GLD16(kb + (size_t)r * E_ + c * 8, &Ks[0][i * 8]);
            GLD16(vb + (size_t)r * S_ + c * 8, &Vs[0][i * 8]);
        }
        __syncthreads();

        short8 qf[2];   // Q fragment lives in registers; QP is dead for Q after this
        #pragma unroll
        for (int ks = 0; ks < 2; ++ks) {
            int row = wid * 16 + qloc;
            int c = (g + 4 * ks) ^ (row & 7);
            qf[ks] = *(const short8*)&QP[row * 64 + c * 8];
        }

        floatx4 o[4] = {};
        float mr = NEG_INF, lr = 0.f;

        int buf = 0;
        for (int jt = 0; jt <= qt; ++jt) {
            // issue next tile's staging BEFORE compute (latency hides under compute)
            if (jt < qt) {
                #pragma unroll
                for (int it = 0; it < 2; ++it) {
                    int i = it * 256 + t;
                    int r = i >> 3, cs = i & 7, c = cs ^ (r & 7);
                    GLD16(kb + (size_t)((jt + 1) * 64 + r) * E_ + c * 8, &Ks[buf ^ 1][i * 8]);
                    GLD16(vb + (size_t)r * S_ + (jt + 1) * 64 + c * 8, &Vs[buf ^ 1][i * 8]);
                }
            }

            // S = Q K^T, SWAPPED operands: s[nf][r] = S[q = wid*16+qloc][kv = 16nf+4g+r]
            floatx4 s[4] = {};
            #pragma unroll
            for (int nf = 0; nf < 4; ++nf) {
                #pragma unroll
                for (int ks = 0; ks < 2; ++ks) {
                    int row = 16 * nf + qloc;
                    int c = (g + 4 * ks) ^ (row & 7);
                    short8 kf = *(const short8*)&Ks[buf][row * 64 + c * 8];
                    s[nf] = __builtin_amdgcn_mfma_f32_16x16x32_bf16(kf, qf[ks], s[nf], 0, 0, 0);
                }
            }

            // causal mask on diagonal tile only (raw scores, -inf); kv > q within tile
            if (jt == qt) {
                int qrow = wid * 16 + qloc;
                #pragma unroll
                for (int nf = 0; nf < 4; ++nf)
                    #pragma unroll
                    for (int r = 0; r < 4; ++r)
                        if (16 * nf + 4 * g + r > qrow) s[nf][r] = NEG_INF;
            }

            // row max: 15 in-lane fmax + 2 cross-lane (xor16, xor32); defer-max check
            float mx = s[0][0];
            #pragma unroll
            for (int nf = 0; nf < 4; ++nf)
                #pragma unroll
                for (int r = 0; r < 4; ++r) mx = fmaxf(mx, s[nf][r]);
            mx = fmaxf(mx, __shfl_xor(mx, 16));
            mx = fmaxf(mx, __shfl_xor(mx, 32));
            bool ok = (mx - mr) * SC <= 8.0f;

            if (!__all(ok)) {   // rescale path (rare after warm-up)
                float mn = fmaxf(mr, mx);
                float al = fast_exp2((mr - mn) * SC);
                mr = mn;
                lr *= al;
                #pragma unroll
                for (int r = 0; r < 4; ++r) {      // o rows are q-local 4g+r -> pull their alpha
                    float alq = lane_pull(al, 4 * g + r);
                    #pragma unroll
                    for (int nf = 0; nf < 4; ++nf) o[nf][r] *= alq;
                }
            }

            // exp2(fma) + lane-partial row sum (fully lane-local)
            {
                float nm = -mr * SC;
                float rs = 0.f;
                #pragma unroll
                for (int nf = 0; nf < 4; ++nf)
                    #pragma unroll
                    for (int r = 0; r < 4; ++r) {
                        float p = fast_exp2(fmaf(s[nf][r], SC, nm));
                        s[nf][r] = p;
                        rs += p;
                    }
                lr += rs;
            }

            // P -> wave-private quarter: 4 contiguous kv per nf -> ONE b64 write
            #pragma unroll
            for (int nf = 0; nf < 4; ++nf) {
                unsigned pk0 = cvt_pk_bf16(s[nf][0], s[nf][1]);
                unsigned pk1 = cvt_pk_bf16(s[nf][2], s[nf][3]);
                int chunk = 2 * nf + (g >> 1);
                int sw = chunk ^ (qloc & 7);
                int a = qloc * 64 + sw * 8 + 4 * (g & 1);
                *(uint2*)&Pw[a] = make_uint2(pk0, pk1);
            }

            // O += P V (A-frag read matches the written [q][kv] layout)
            short8 pf[2];
            #pragma unroll
            for (int ks = 0; ks < 2; ++ks) {
                int row = l & 15;
                int c = (g + 4 * ks) ^ (row & 7);
                pf[ks] = *(const short8*)&Pw[row * 64 + c * 8];
            }
            #pragma unroll
            for (int nf = 0; nf < 4; ++nf) {
                #pragma unroll
                for (int ks = 0; ks < 2; ++ks) {
                    int row = 16 * nf + (l & 15);
                    int c = (g + 4 * ks) ^ (row & 7);
                    short8 vf = *(const short8*)&Vs[buf][row * 64 + c * 8];
                    o[nf] = __builtin_amdgcn_mfma_f32_16x16x32_bf16(pf[ks], vf, o[nf], 0, 0, 0);
                }
            }

            __syncthreads();   // drains this iteration's prefetch (vmcnt) + protects buf^1
            buf ^= 1;
        }

        // epilogue: complete row sums (xor16+xor32), distribute 1/l to o-rows, write out
        lr += __shfl_xor(lr, 16);
        lr += __shfl_xor(lr, 32);
        float inv = 1.0f / lr;
        float il[4];
        #pragma unroll
        for (int r = 0; r < 4; ++r) il[r] = lane_pull(inv, 4 * g + r);

        #pragma unroll
        for (int nf = 0; nf < 4; ++nf) {
            int col = 16 * nf + qloc;
            #pragma unroll
            for (int rp = 0; rp < 2; ++rp) {
                unsigned pk = cvt_pk_bf16(o[nf][2 * rp] * il[2 * rp],
                                          o[nf][2 * rp + 1] * il[2 * rp + 1]);
                int row0 = g * 4 + 2 * rp;
                int a0 = row0 * 64 + (((col >> 3)) ^ (row0 & 7)) * 8 + (col & 7);
                int a1 = (row0 + 1) * 64 + (((col >> 3)) ^ ((row0 + 1) & 7)) * 8 + (col & 7);
                Pw[a0] = (ushort)pk;
                Pw[a1] = (ushort)(pk >> 16);
            }
        }
        #pragma unroll
        for (int it = 0; it < 2; ++it) {               // 16 rows x 8 chunks per wave
            int i = it * 64 + l;
            int row = i >> 3, cc = i & 7;
            int c = cc ^ (row & 7);
            short8 vv = *(const short8*)&Pw[row * 64 + c * 8];
            int s_abs = qt * 64 + wid * 16 + row;
            *(short8*)&attn[((size_t)(b * S_ + s_abs)) * D_ + h * E_ + cc * 8] = vv;
        }
        __syncthreads();   // all waves done with QP before next q-tile's Q staging
    }
}

// ---------------- output projection: [8192x1024] x Wp^T + bp, bf16 MFMA, fp32 out ----------------
__global__ __launch_bounds__(256) void out_proj(const ushort* __restrict__ a,
                                                const ushort* __restrict__ wpb,
                                                const float* __restrict__ bp,
                                                float* __restrict__ out) {
    const int m0 = blockIdx.x * 128;
    const int n0 = blockIdx.y * 128;

    __shared__ __align__(16) ushort As[128 * 32];
    __shared__ __align__(16) ushort Bs[128 * 32];

    const int t = threadIdx.x, l = t & 63, wid = t >> 6;
    const int wm = (wid & 1) * 64, wn = (wid >> 1) * 64;
    floatx4 acc[4][4] = {};

    for (int k0 = 0; k0 < D_; k0 += 32) {
        __syncthreads();
        #pragma unroll
        for (int it = 0; it < 2; ++it) {
            int i = it * 256 + t;
            int r = i >> 2, cs = i & 3;
            int c = cs ^ ((r >> 1) & 3);
            GLD16(a + (size_t)(m0 + r) * D_ + k0 + c * 8, &As[i * 8]);
            GLD16(wpb + (size_t)(n0 + r) * D_ + k0 + c * 8, &Bs[i * 8]);
        }
        __syncthreads();

        short8 af[4], bf[4];
        #pragma unroll
        for (int mf = 0; mf < 4; ++mf) {
            int row = wm + 16 * mf + (l & 15);
            int c = (l >> 4) ^ ((row >> 1) & 3);
            af[mf] = *(const short8*)&As[row * 32 + c * 8];
        }
        #pragma unroll
        for (int nf = 0; nf < 4; ++nf) {
            int row = wn + 16 * nf + (l & 15);
            int c = (l >> 4) ^ ((row >> 1) & 3);
            bf[nf] = *(const short8*)&Bs[row * 32 + c * 8];
        }
        #pragma unroll
        for (int mf = 0; mf < 4; ++mf)
            #pragma unroll
            for (int nf = 0; nf < 4; ++nf)
                acc[mf][nf] = __builtin_amdgcn_mfma_f32_16x16x32_bf16(af[mf], bf[nf], acc[mf][nf], 0, 0, 0);
    }

    #pragma unroll
    for (int nf = 0; nf < 4; ++nf) {
        int col = n0 + wn + 16 * nf + (l & 15);
        float bias = bp[col];
        #pragma unroll
        for (int mf = 0; mf < 4; ++mf)
            #pragma unroll
            for (int r = 0; r < 4; ++r) {
                int m = m0 + wm + 16 * mf + (l >> 4) * 4 + r;
                out[(size_t)m * D_ + col] = acc[mf][nf][r] + bias;
            }
    }
}

extern "C" void kernel_launch(void* const* d_in, const int* in_sizes, int n_in,
                              void* d_out, int out_size, void* d_ws, size_t ws_size,
                              hipStream_t stream) {
    const float* x  = (const float*)d_in[0];
    const float* Wq = (const float*)d_in[1];
    const float* Wk = (const float*)d_in[2];
    const float* Wv = (const float*)d_in[3];
    const float* Wp = (const float*)d_in[4];
    const float* bp = (const float*)d_in[5];

    ushort* ws = (ushort*)d_ws;
    const size_t NX  = (size_t)M_ * D_;          // 8M
    const size_t NW  = (size_t)48 * E_ * D_;     // 3.15M
    const size_t NP  = (size_t)D_ * D_;          // 1M
    const size_t QSZ = (size_t)B_ * H_ * S_ * E_;// 8M
    ushort* xb    = ws;
    ushort* wt    = xb + NX;
    ushort* wpb   = wt + NW;
    ushort* qk    = wpb + NP;        // q | k
    ushort* vt    = qk + 2 * QSZ;    // v, transposed [bh][e][s]
    ushort* attnb = vt + QSZ;

    cast_bf16  <<<2048, 256, 0, stream>>>(x, xb, (int)(NX / 8));
    cast_bf16  <<<512, 256, 0, stream>>>(Wp, wpb, (int)(NP / 8));
    transpose_w<<<dim3(16, 48), 256, 0, stream>>>(Wq, Wk, Wv, wt);
    gemm_qkv   <<<dim3(M_ / 256, 24), 512, 0, stream>>>(xb, wt, qk, vt);
    flash      <<<1024, 256, 0, stream>>>(qk, qk + QSZ, vt, attnb);
    out_proj   <<<dim3(M_ / 128, D_ / 128), 256, 0, stream>>>(attnb, wpb, bp, (float*)d_out);
}